// Round 1
// baseline (2491.511 us; speedup 1.0000x reference)
//
#include <hip/hip_runtime.h>

#pragma clang fp contract(off)

#define B 16
#define A 3
#define HGT 52
#define WID 52
#define HW 2704
#define NCAND 8112   // A*HW
#define CATTR 25
#define TOPK 2048
#define SORTN 8192

// ---------------- decode ----------------
// out[b, n, c] with n = a*HW + h*W + w ; (cx,cy,bw,bh,conf,cls0..19)
__global__ void decode_kernel(const float* __restrict__ inp,
                              const float* __restrict__ anchors,
                              float* __restrict__ out) {
    int t = blockIdx.x * blockDim.x + threadIdx.x;
    if (t >= B * NCAND) return;
    int b  = t / NCAND;
    int n  = t - b * NCAND;
    int a  = n / HW;
    int hw = n - a * HW;
    int gy = hw / WID;
    int gx = hw - gy * WID;
    const float* ip = inp + ((size_t)(b * (A * CATTR) + a * CATTR)) * HW + hw;
    float* op = out + (size_t)t * CATTR;

    float p0 = ip[0 * HW], p1 = ip[1 * HW], p2 = ip[2 * HW], p3 = ip[3 * HW], p4 = ip[4 * HW];
    float sx = 1.0f / (1.0f + expf(-p0));
    float sy = 1.0f / (1.0f + expf(-p1));
    float bx = (sx + (float)gx) * 8.0f;   // stride_w = 416/52 = 8 exactly
    float by = (sy + (float)gy) * 8.0f;
    // (anchor/8)*8 is exact -> bw = exp(w)*anchor
    float bw = expf(p2) * anchors[a * 2 + 0];
    float bh = expf(p3) * anchors[a * 2 + 1];
    float cf = 1.0f / (1.0f + expf(-p4));
    op[0] = bx; op[1] = by; op[2] = bw; op[3] = bh; op[4] = cf;
#pragma unroll
    for (int c = 0; c < 20; ++c) {
        float v = ip[(5 + c) * HW];
        op[5 + c] = 1.0f / (1.0f + expf(-v));
    }
}

// ---------------- top-k via full bitonic sort ----------------
// key = (~(conf_bits | signbit) << 32) | index ; ascending sort ==
// conf descending, index ascending tie-break (== jax.lax.top_k stable order)
__global__ __launch_bounds__(1024) void sort_kernel(const float* __restrict__ out,
                                                    float* __restrict__ topf) {
    __shared__ unsigned long long keys[SORTN];   // 64 KiB
    int b = blockIdx.x;
    int tid = threadIdx.x;
    for (int n = tid; n < SORTN; n += 1024) {
        unsigned long long key;
        if (n < NCAND) {
            float cf = out[((size_t)b * NCAND + n) * CATTR + 4];
            unsigned bits = __float_as_uint(cf) | 0x80000000u;  // conf > 0 always
            key = ((unsigned long long)(~bits) << 32) | (unsigned)n;
        } else {
            key = ~0ull;   // pad sorts last
        }
        keys[n] = key;
    }
    for (unsigned k = 2; k <= SORTN; k <<= 1) {
        for (unsigned j = k >> 1; j > 0; j >>= 1) {
            __syncthreads();
            for (unsigned ii = tid; ii < SORTN; ii += 1024) {
                unsigned l = ii ^ j;
                if (l > ii) {
                    unsigned long long va = keys[ii], vb = keys[l];
                    bool up = ((ii & k) == 0);
                    if ((va > vb) == up) { keys[ii] = vb; keys[l] = va; }
                }
            }
        }
    }
    __syncthreads();
    for (int r = tid; r < TOPK; r += 1024) {
        topf[(size_t)b * TOPK + r] = (float)(unsigned)(keys[r] & 0xFFFFFFFFu);
    }
}

// ---------------- greedy class-aware NMS ----------------
__global__ __launch_bounds__(256) void nms_kernel(const float* __restrict__ out,
                                                  const float* __restrict__ topf,
                                                  float* __restrict__ keepf) {
    __shared__ float sx1[TOPK], sy1[TOPK], sx2[TOPK], sy2[TOPK], sar[TOPK]; // 40 KiB
    __shared__ unsigned char scls[TOPK], sval[TOPK], ssup[TOPK], skeep[TOPK]; // 8 KiB
    int b = blockIdx.x;
    int tid = threadIdx.x;

    for (int r = tid; r < TOPK; r += 256) {
        int idx = (int)topf[(size_t)b * TOPK + r];
        const float* p = out + ((size_t)b * NCAND + idx) * CATTR;
        float cx = p[0], cy = p[1], w = p[2], h = p[3], cf = p[4];
        float hw_ = w * 0.5f, hh_ = h * 0.5f;   // w/2 exact
        float x1 = cx - hw_, y1 = cy - hh_, x2 = cx + hw_, y2 = cy + hh_;
        sx1[r] = x1; sy1[r] = y1; sx2[r] = x2; sy2[r] = y2;
        sar[r] = ((x2 - x1) + 1.0f) * ((y2 - y1) + 1.0f);
        float best = p[5]; int bc = 0;
#pragma unroll
        for (int c = 1; c < 20; ++c) {          // first-max argmax (numpy semantics)
            float v = p[5 + c];
            if (v > best) { best = v; bc = c; }
        }
        scls[r] = (unsigned char)bc;
        sval[r] = (cf >= 0.5f) ? 1 : 0;
        ssup[r] = 0;
    }
    __syncthreads();

    bool pending = false;   // uniform across block: did last iteration write ssup?
    for (int i = 0; i < TOPK; ++i) {
        if (pending) { __syncthreads(); pending = false; }
        bool ki = sval[i] && !ssup[i];          // uniform broadcast reads
        if (tid == 0) skeep[i] = ki ? 1 : 0;
        if (ki) {
            float bx1 = sx1[i], by1 = sy1[i], bx2 = sx2[i], by2 = sy2[i], ba = sar[i];
            int bc = scls[i];
            for (int j = tid; j < TOPK; j += 256) {   // ssup[j]: single-writer (tid)
                if (j > i && !ssup[j] && scls[j] == bc) {
                    float ix1 = fmaxf(bx1, sx1[j]);
                    float iy1 = fmaxf(by1, sy1[j]);
                    float ix2 = fminf(bx2, sx2[j]);
                    float iy2 = fminf(by2, sy2[j]);
                    float iw = fmaxf((ix2 - ix1) + 1.0f, 0.0f);
                    float ih = fmaxf((iy2 - iy1) + 1.0f, 0.0f);
                    float inter = iw * ih;
                    float iou = inter / (((ba + sar[j]) - inter) + 1e-16f);
                    if (iou >= 0.4f) ssup[j] = 1;
                }
            }
            pending = true;
        }
    }
    __syncthreads();
    for (int r = tid; r < TOPK; r += 256) {
        keepf[(size_t)b * TOPK + r] = skeep[r] ? 1.0f : 0.0f;
    }
}

extern "C" void kernel_launch(void* const* d_in, const int* in_sizes, int n_in,
                              void* d_out, int out_size, void* d_ws, size_t ws_size,
                              hipStream_t stream) {
    const float* inp     = (const float*)d_in[0];
    const float* anchors = (const float*)d_in[1];
    float* out   = (float*)d_out;                        // [B, N, 25]
    float* topf  = out  + (size_t)B * NCAND * CATTR;     // [B, 2048] indices as float
    float* keepf = topf + (size_t)B * TOPK;              // [B, 2048] 0/1 as float

    int total = B * NCAND;
    decode_kernel<<<(total + 255) / 256, 256, 0, stream>>>(inp, anchors, out);
    sort_kernel<<<B, 1024, 0, stream>>>(out, topf);
    nms_kernel<<<B, 256, 0, stream>>>(out, topf, keepf);
}

// Round 2
// 902.211 us; speedup vs baseline: 2.7616x; 2.7616x over previous
//
#include <hip/hip_runtime.h>

#pragma clang fp contract(off)

#define B 16
#define A 3
#define HGT 52
#define WID 52
#define HW 2704
#define NCAND 8112   // A*HW
#define CATTR 25
#define TOPK 2048
#define SORTN 8192
#define NWORD 64     // 64 words x 32 bits = 2048 cols

typedef unsigned int uint32;

// ---------------- decode ----------------
__global__ void decode_kernel(const float* __restrict__ inp,
                              const float* __restrict__ anchors,
                              float* __restrict__ out) {
    int t = blockIdx.x * blockDim.x + threadIdx.x;
    if (t >= B * NCAND) return;
    int b  = t / NCAND;
    int n  = t - b * NCAND;
    int a  = n / HW;
    int hw = n - a * HW;
    int gy = hw / WID;
    int gx = hw - gy * WID;
    const float* ip = inp + ((size_t)(b * (A * CATTR) + a * CATTR)) * HW + hw;
    float* op = out + (size_t)t * CATTR;

    float p0 = ip[0 * HW], p1 = ip[1 * HW], p2 = ip[2 * HW], p3 = ip[3 * HW], p4 = ip[4 * HW];
    float sx = 1.0f / (1.0f + expf(-p0));
    float sy = 1.0f / (1.0f + expf(-p1));
    float bx = (sx + (float)gx) * 8.0f;   // stride = 8 exactly
    float by = (sy + (float)gy) * 8.0f;
    float bw = expf(p2) * anchors[a * 2 + 0];   // (anchor/8)*8 exact
    float bh = expf(p3) * anchors[a * 2 + 1];
    float cf = 1.0f / (1.0f + expf(-p4));
    op[0] = bx; op[1] = by; op[2] = bw; op[3] = bh; op[4] = cf;
#pragma unroll
    for (int c = 0; c < 20; ++c) {
        float v = ip[(5 + c) * HW];
        op[5 + c] = 1.0f / (1.0f + expf(-v));
    }
}

// ---------------- top-k via full bitonic sort ----------------
__global__ __launch_bounds__(1024) void sort_kernel(const float* __restrict__ out,
                                                    float* __restrict__ topf) {
    __shared__ unsigned long long keys[SORTN];   // 64 KiB
    int b = blockIdx.x;
    int tid = threadIdx.x;
    for (int n = tid; n < SORTN; n += 1024) {
        unsigned long long key;
        if (n < NCAND) {
            float cf = out[((size_t)b * NCAND + n) * CATTR + 4];
            unsigned bits = __float_as_uint(cf) | 0x80000000u;  // conf > 0 always
            key = ((unsigned long long)(~bits) << 32) | (unsigned)n;
        } else {
            key = ~0ull;
        }
        keys[n] = key;
    }
    for (unsigned k = 2; k <= SORTN; k <<= 1) {
        for (unsigned j = k >> 1; j > 0; j >>= 1) {
            __syncthreads();
            for (unsigned ii = tid; ii < SORTN; ii += 1024) {
                unsigned l = ii ^ j;
                if (l > ii) {
                    unsigned long long va = keys[ii], vb = keys[l];
                    bool up = ((ii & k) == 0);
                    if ((va > vb) == up) { keys[ii] = vb; keys[l] = va; }
                }
            }
        }
    }
    __syncthreads();
    for (int r = tid; r < TOPK; r += 1024) {
        topf[(size_t)b * TOPK + r] = (float)(unsigned)(keys[r] & 0xFFFFFFFFu);
    }
}

// ---------------- NMS stage 1: per-candidate geometry ----------------
__global__ __launch_bounds__(256) void geo_kernel(const float* __restrict__ out,
                                                  const float* __restrict__ topf,
                                                  float* __restrict__ gx1,
                                                  float* __restrict__ gy1,
                                                  float* __restrict__ gx2,
                                                  float* __restrict__ gy2,
                                                  float* __restrict__ gar,
                                                  uint32* __restrict__ gcv) {
    int t = blockIdx.x * blockDim.x + threadIdx.x;
    if (t >= B * TOPK) return;
    int b = t >> 11;            // /2048
    int r = t & (TOPK - 1);
    int idx = (int)topf[(size_t)b * TOPK + r];
    const float* p = out + ((size_t)b * NCAND + idx) * CATTR;
    float cx = p[0], cy = p[1], w = p[2], h = p[3], cf = p[4];
    float hw_ = w * 0.5f, hh_ = h * 0.5f;  // w/2 exact
    float x1 = cx - hw_, y1 = cy - hh_, x2 = cx + hw_, y2 = cy + hh_;
    gx1[t] = x1; gy1[t] = y1; gx2[t] = x2; gy2[t] = y2;
    gar[t] = ((x2 - x1) + 1.0f) * ((y2 - y1) + 1.0f);
    float best = p[5]; int bc = 0;
#pragma unroll
    for (int c = 1; c < 20; ++c) {       // first-max argmax (numpy semantics)
        float v = p[5 + c];
        if (v > best) { best = v; bc = c; }
    }
    uint32 valid = (cf >= 0.5f) ? 1u : 0u;
    gcv[t] = (uint32)bc | (valid << 8);
}

// ---------------- NMS stage 2: suppression bitmask build ----------------
// block: 1024 thr = 16 row-groups x 64 words; 4 rows/thread -> 64 rows/block
// grid: (TOPK/64, B)
// LDS columns swizzled: col j stored at s(j) = (j&31)*64 + (j>>5)
//   -> inner loop (b2 fixed, w=lane) reads consecutive addresses: conflict-free
__global__ __launch_bounds__(1024) void build_kernel(const float* __restrict__ gx1,
                                                     const float* __restrict__ gy1,
                                                     const float* __restrict__ gx2,
                                                     const float* __restrict__ gy2,
                                                     const float* __restrict__ gar,
                                                     const uint32* __restrict__ gcv,
                                                     uint32* __restrict__ rowmask) {
    __shared__ float4 x4s[TOPK];    // 32 KiB
    __shared__ float  ars[TOPK];    // 8 KiB
    __shared__ uint32 clss[TOPK];   // 8 KiB
    int bt  = blockIdx.y;
    int tid = threadIdx.x;
    int base = bt * TOPK;

    for (int s = tid; s < TOPK; s += 1024) {
        int j = (s & 63) * 32 + (s >> 6);   // inverse swizzle
        int g = base + j;
        x4s[s]  = make_float4(gx1[g], gy1[g], gx2[g], gy2[g]);
        ars[s]  = gar[g];
        clss[s] = gcv[g] & 0xffu;
    }
    __syncthreads();

    int w  = tid & 63;
    int rg = tid >> 6;
    int i0 = blockIdx.x * 64 + rg * 4;

    float rx1[4], ry1[4], rx2[4], ry2[4], rar[4];
    uint32 rcl[4];
#pragma unroll
    for (int r = 0; r < 4; ++r) {
        int g = base + i0 + r;
        rx1[r] = gx1[g]; ry1[r] = gy1[g]; rx2[r] = gx2[g]; ry2[r] = gy2[g];
        rar[r] = gar[g]; rcl[r] = gcv[g] & 0xffu;
    }
    uint32 word[4] = {0u, 0u, 0u, 0u};

    for (int b2 = 0; b2 < 32; ++b2) {
        int sidx = b2 * 64 + w;
        float4 c  = x4s[sidx];
        float car = ars[sidx];
        uint32 cc = clss[sidx];
#pragma unroll
        for (int r = 0; r < 4; ++r) {
            float ix1 = fmaxf(rx1[r], c.x);
            float iy1 = fmaxf(ry1[r], c.y);
            float ix2 = fminf(rx2[r], c.z);
            float iy2 = fminf(ry2[r], c.w);
            float iw = fmaxf((ix2 - ix1) + 1.0f, 0.0f);
            float ih = fmaxf((iy2 - iy1) + 1.0f, 0.0f);
            float inter = iw * ih;
            float iou = inter / (((rar[r] + car) - inter) + 1e-16f);
            if ((iou >= 0.4f) && (cc == rcl[r])) word[r] |= 1u << b2;
        }
    }
#pragma unroll
    for (int r = 0; r < 4; ++r) {
        rowmask[((size_t)(base + i0 + r)) * NWORD + w] = word[r];
    }
}

// ---------------- NMS stage 3: serial greedy scan, 1 wave/batch ----------------
// lane l owns supp bits [l*32, l*32+32). All lanes redundantly track `cur`
// (the supp word of the current 32-group) so the per-iteration decision needs
// no cross-lane op: kf = valid & ~cur bit; cur/supp |= row words (masked).
#define PF 16
__global__ __launch_bounds__(64) void scan_kernel(const uint32* __restrict__ rowmask,
                                                  const uint32* __restrict__ gcv,
                                                  float* __restrict__ keepf) {
    int bt = blockIdx.x;
    int l  = threadIdx.x;   // 0..63
    const uint32* rm = rowmask + (size_t)bt * TOPK * NWORD;

    uint32 vword = 0;
#pragma unroll
    for (int k = 0; k < 32; ++k)
        vword |= ((gcv[bt * TOPK + l * 32 + k] >> 8) & 1u) << k;

    uint32 supp = 0, keepw = 0, cur = 0, vcur = 0;
    uint32 pl[PF], pw[PF];
#pragma unroll
    for (int k = 0; k < PF; ++k) {
        pl[k] = rm[k * NWORD + l];
        pw[k] = rm[k * NWORD + (k >> 5)];
    }
    for (int ii = 0; ii < TOPK; ii += PF) {
#pragma unroll
        for (int k = 0; k < PF; ++k) {
            int i = ii + k;
            uint32 rl = pl[k], rw = pw[k];
            int nx = i + PF;
            if (nx < TOPK) {
                pl[k] = rm[nx * NWORD + l];
                pw[k] = rm[nx * NWORD + (nx >> 5)];
            }
            int b2 = i & 31;
            if (b2 == 0) {                 // group start: rebroadcast supp word
                int wg = i >> 5;
                cur  = __shfl(supp, wg);
                vcur = __shfl(vword, wg);
            }
            uint32 kf = (vcur >> b2) & (~(cur >> b2)) & 1u;   // uniform
            uint32 m = (uint32)(-(int)kf);
            cur  |= rw & m;
            supp |= rl & m;
            if (l == (i >> 5)) keepw |= kf << b2;
        }
    }
#pragma unroll
    for (int k = 0; k < 32; ++k)
        keepf[bt * TOPK + l * 32 + k] = (float)((keepw >> k) & 1u);
}

extern "C" void kernel_launch(void* const* d_in, const int* in_sizes, int n_in,
                              void* d_out, int out_size, void* d_ws, size_t ws_size,
                              hipStream_t stream) {
    const float* inp     = (const float*)d_in[0];
    const float* anchors = (const float*)d_in[1];
    float* out   = (float*)d_out;                        // [B, N, 25]
    float* topf  = out  + (size_t)B * NCAND * CATTR;     // [B, 2048] indices as float
    float* keepf = topf + (size_t)B * TOPK;              // [B, 2048] 0/1 as float

    // workspace layout
    float*  gx1 = (float*)d_ws;
    float*  gy1 = gx1 + B * TOPK;
    float*  gx2 = gy1 + B * TOPK;
    float*  gy2 = gx2 + B * TOPK;
    float*  gar = gy2 + B * TOPK;
    uint32* gcv = (uint32*)(gar + B * TOPK);
    uint32* rowmask = gcv + B * TOPK;                    // 16*2048*64 u32 = 8 MiB

    int total = B * NCAND;
    decode_kernel<<<(total + 255) / 256, 256, 0, stream>>>(inp, anchors, out);
    sort_kernel<<<B, 1024, 0, stream>>>(out, topf);
    geo_kernel<<<(B * TOPK + 255) / 256, 256, 0, stream>>>(out, topf, gx1, gy1, gx2, gy2, gar, gcv);
    build_kernel<<<dim3(TOPK / 64, B), 1024, 0, stream>>>(gx1, gy1, gx2, gy2, gar, gcv, rowmask);
    scan_kernel<<<B, 64, 0, stream>>>(rowmask, gcv, keepf);
}

// Round 3
// 307.920 us; speedup vs baseline: 8.0914x; 2.9300x over previous
//
#include <hip/hip_runtime.h>

#pragma clang fp contract(off)

#define B 16
#define A 3
#define HGT 52
#define WID 52
#define HW 2704
#define NCAND 8112   // A*HW
#define CATTR 25
#define TOPK 2048
#define SORTN 8192
#define NWORD 64     // 64 words x 32 bits = 2048 cols
#define CH 64        // rows per scan chunk
#define NCHUNK (TOPK / CH)

typedef unsigned int uint32;

// ---------------- decode ----------------
__global__ void decode_kernel(const float* __restrict__ inp,
                              const float* __restrict__ anchors,
                              float* __restrict__ out) {
    int t = blockIdx.x * blockDim.x + threadIdx.x;
    if (t >= B * NCAND) return;
    int b  = t / NCAND;
    int n  = t - b * NCAND;
    int a  = n / HW;
    int hw = n - a * HW;
    int gy = hw / WID;
    int gx = hw - gy * WID;
    const float* ip = inp + ((size_t)(b * (A * CATTR) + a * CATTR)) * HW + hw;
    float* op = out + (size_t)t * CATTR;

    float p0 = ip[0 * HW], p1 = ip[1 * HW], p2 = ip[2 * HW], p3 = ip[3 * HW], p4 = ip[4 * HW];
    float sx = 1.0f / (1.0f + expf(-p0));
    float sy = 1.0f / (1.0f + expf(-p1));
    float bx = (sx + (float)gx) * 8.0f;   // stride = 8 exactly
    float by = (sy + (float)gy) * 8.0f;
    float bw = expf(p2) * anchors[a * 2 + 0];   // (anchor/8)*8 exact
    float bh = expf(p3) * anchors[a * 2 + 1];
    float cf = 1.0f / (1.0f + expf(-p4));
    op[0] = bx; op[1] = by; op[2] = bw; op[3] = bh; op[4] = cf;
#pragma unroll
    for (int c = 0; c < 20; ++c) {
        float v = ip[(5 + c) * HW];
        op[5 + c] = 1.0f / (1.0f + expf(-v));
    }
}

// ---------------- top-k via full bitonic sort ----------------
__global__ __launch_bounds__(1024) void sort_kernel(const float* __restrict__ out,
                                                    float* __restrict__ topf) {
    __shared__ unsigned long long keys[SORTN];   // 64 KiB
    int b = blockIdx.x;
    int tid = threadIdx.x;
    for (int n = tid; n < SORTN; n += 1024) {
        unsigned long long key;
        if (n < NCAND) {
            float cf = out[((size_t)b * NCAND + n) * CATTR + 4];
            unsigned bits = __float_as_uint(cf) | 0x80000000u;  // conf > 0 always
            key = ((unsigned long long)(~bits) << 32) | (unsigned)n;
        } else {
            key = ~0ull;
        }
        keys[n] = key;
    }
    for (unsigned k = 2; k <= SORTN; k <<= 1) {
        for (unsigned j = k >> 1; j > 0; j >>= 1) {
            __syncthreads();
            for (unsigned ii = tid; ii < SORTN; ii += 1024) {
                unsigned l = ii ^ j;
                if (l > ii) {
                    unsigned long long va = keys[ii], vb = keys[l];
                    bool up = ((ii & k) == 0);
                    if ((va > vb) == up) { keys[ii] = vb; keys[l] = va; }
                }
            }
        }
    }
    __syncthreads();
    for (int r = tid; r < TOPK; r += 1024) {
        topf[(size_t)b * TOPK + r] = (float)(unsigned)(keys[r] & 0xFFFFFFFFu);
    }
}

// ---------------- NMS stage 1: per-candidate geometry + valid-bit pack ----
__global__ __launch_bounds__(256) void geo_kernel(const float* __restrict__ out,
                                                  const float* __restrict__ topf,
                                                  float* __restrict__ gx1,
                                                  float* __restrict__ gy1,
                                                  float* __restrict__ gx2,
                                                  float* __restrict__ gy2,
                                                  float* __restrict__ gar,
                                                  uint32* __restrict__ gcv,
                                                  uint32* __restrict__ vwords) {
    int t = blockIdx.x * blockDim.x + threadIdx.x;
    if (t >= B * TOPK) return;
    int b = t >> 11;            // /2048
    int r = t & (TOPK - 1);
    int idx = (int)topf[(size_t)b * TOPK + r];
    const float* p = out + ((size_t)b * NCAND + idx) * CATTR;
    float cx = p[0], cy = p[1], w = p[2], h = p[3], cf = p[4];
    float hw_ = w * 0.5f, hh_ = h * 0.5f;  // w/2 exact
    float x1 = cx - hw_, y1 = cy - hh_, x2 = cx + hw_, y2 = cy + hh_;
    gx1[t] = x1; gy1[t] = y1; gx2[t] = x2; gy2[t] = y2;
    gar[t] = ((x2 - x1) + 1.0f) * ((y2 - y1) + 1.0f);
    float best = p[5]; int bc = 0;
#pragma unroll
    for (int c = 1; c < 20; ++c) {       // first-max argmax (numpy semantics)
        float v = p[5 + c];
        if (v > best) { best = v; bc = c; }
    }
    bool valid = (cf >= 0.5f);
    gcv[t] = (uint32)bc | (valid ? 0x100u : 0u);
    unsigned long long bal = __ballot(valid);   // t is wave-aligned (grid % 64 == 0)
    if ((t & 63) == 0) {
        vwords[(t >> 5) + 0] = (uint32)bal;
        vwords[(t >> 5) + 1] = (uint32)(bal >> 32);
    }
}

// ---------------- NMS stage 2: suppression bitmask build ----------------
// block: 1024 thr = 16 row-groups x 64 words; 4 rows/thread -> 64 rows/block
// grid: (TOPK/64, B)
// LDS columns swizzled: col j stored at s(j) = (j&31)*64 + (j>>5)
__global__ __launch_bounds__(1024) void build_kernel(const float* __restrict__ gx1,
                                                     const float* __restrict__ gy1,
                                                     const float* __restrict__ gx2,
                                                     const float* __restrict__ gy2,
                                                     const float* __restrict__ gar,
                                                     const uint32* __restrict__ gcv,
                                                     uint32* __restrict__ rowmask) {
    __shared__ float4 x4s[TOPK];    // 32 KiB
    __shared__ float  ars[TOPK];    // 8 KiB
    __shared__ uint32 clss[TOPK];   // 8 KiB
    int bt  = blockIdx.y;
    int tid = threadIdx.x;
    int base = bt * TOPK;

    for (int s = tid; s < TOPK; s += 1024) {
        int j = (s & 63) * 32 + (s >> 6);   // inverse swizzle
        int g = base + j;
        x4s[s]  = make_float4(gx1[g], gy1[g], gx2[g], gy2[g]);
        ars[s]  = gar[g];
        clss[s] = gcv[g] & 0xffu;
    }
    __syncthreads();

    int w  = tid & 63;
    int rg = tid >> 6;
    int i0 = blockIdx.x * 64 + rg * 4;

    float rx1[4], ry1[4], rx2[4], ry2[4], rar[4];
    uint32 rcl[4];
#pragma unroll
    for (int r = 0; r < 4; ++r) {
        int g = base + i0 + r;
        rx1[r] = gx1[g]; ry1[r] = gy1[g]; rx2[r] = gx2[g]; ry2[r] = gy2[g];
        rar[r] = gar[g]; rcl[r] = gcv[g] & 0xffu;
    }
    uint32 word[4] = {0u, 0u, 0u, 0u};

    for (int b2 = 0; b2 < 32; ++b2) {
        int sidx = b2 * 64 + w;
        float4 c  = x4s[sidx];
        float car = ars[sidx];
        uint32 cc = clss[sidx];
#pragma unroll
        for (int r = 0; r < 4; ++r) {
            float ix1 = fmaxf(rx1[r], c.x);
            float iy1 = fmaxf(ry1[r], c.y);
            float ix2 = fminf(rx2[r], c.z);
            float iy2 = fminf(ry2[r], c.w);
            float iw = fmaxf((ix2 - ix1) + 1.0f, 0.0f);
            float ih = fmaxf((iy2 - iy1) + 1.0f, 0.0f);
            float inter = iw * ih;
            float iou = inter / (((rar[r] + car) - inter) + 1e-16f);
            if ((iou >= 0.4f) && (cc == rcl[r])) word[r] |= 1u << b2;
        }
    }
#pragma unroll
    for (int r = 0; r < 4; ++r) {
        rowmask[((size_t)(base + i0 + r)) * NWORD + w] = word[r];
    }
}

// ---------------- NMS stage 3: serial greedy scan via LDS streaming -------
// 1 block/batch, 512 thr: wave 0 scans chunk c from LDS while waves 1-7
// copy chunk c+1 (16 KB) global->LDS double buffer. Lane l of wave 0 owns
// supp word l; `cur` = supp word of current 32-group, tracked redundantly
// by all lanes so the per-iteration decision has no cross-lane op.
#define SPF 8
__global__ __launch_bounds__(512) void scan_kernel(const uint32* __restrict__ rowmask,
                                                   const uint32* __restrict__ vwords,
                                                   float* __restrict__ keepf) {
    __shared__ uint32 buf[2][CH * NWORD];   // 2 x 16 KiB
    int bt  = blockIdx.x;
    int tid = threadIdx.x;
    int wv  = tid >> 6;
    int l   = tid & 63;
    const uint32* rm = rowmask + (size_t)bt * TOPK * NWORD;

    // chunk 0 copy (waves 1-7)
    if (wv > 0) {
        int ctid = tid - 64;
        const uint4* src = (const uint4*)rm;
        uint4* dst = (uint4*)buf[0];
        for (int o = ctid; o < CH * NWORD / 4; o += 448) dst[o] = src[o];
    }
    uint32 vw = 0, supp = 0, keepw = 0, cur = 0, vcur = 0;
    if (wv == 0) vw = vwords[bt * 64 + l];
    __syncthreads();

    for (int c = 0; c < NCHUNK; ++c) {
        if (wv > 0) {
            if (c + 1 < NCHUNK) {
                int ctid = tid - 64;
                const uint4* src = (const uint4*)(rm + (size_t)(c + 1) * CH * NWORD);
                uint4* dst = (uint4*)buf[(c + 1) & 1];
                for (int o = ctid; o < CH * NWORD / 4; o += 448) dst[o] = src[o];
            }
        } else {
            const uint32* bp = buf[c & 1];
            uint32 rlb[SPF], rwb[SPF];
#pragma unroll
            for (int k = 0; k < SPF; ++k) {
                rlb[k] = bp[k * NWORD + l];
                rwb[k] = bp[k * NWORD + ((c * CH + k) >> 5)];
            }
            for (int kk = 0; kk < CH; kk += SPF) {
#pragma unroll
                for (int k2 = 0; k2 < SPF; ++k2) {
                    int k = kk + k2;
                    int i = c * CH + k;
                    uint32 rl = rlb[k2], rw = rwb[k2];
                    int nk = k + SPF;
                    if (nk < CH) {
                        rlb[k2] = bp[nk * NWORD + l];
                        rwb[k2] = bp[nk * NWORD + ((c * CH + nk) >> 5)];
                    }
                    int b2 = i & 31;
                    if (b2 == 0) {              // group start: rebroadcast
                        cur  = __shfl(supp, i >> 5);
                        vcur = __shfl(vw,   i >> 5);
                    }
                    uint32 kf = ((vcur >> b2) & ~(cur >> b2)) & 1u;
                    uint32 m = (uint32)(-(int)kf);
                    cur  |= rw & m;
                    supp |= rl & m;
                    if (l == (i >> 5)) keepw |= kf << b2;
                }
            }
        }
        __syncthreads();
    }

    if (wv == 0) {
#pragma unroll
        for (int k = 0; k < 32; ++k)
            keepf[bt * TOPK + l * 32 + k] = (float)((keepw >> k) & 1u);
    }
}

extern "C" void kernel_launch(void* const* d_in, const int* in_sizes, int n_in,
                              void* d_out, int out_size, void* d_ws, size_t ws_size,
                              hipStream_t stream) {
    const float* inp     = (const float*)d_in[0];
    const float* anchors = (const float*)d_in[1];
    float* out   = (float*)d_out;                        // [B, N, 25]
    float* topf  = out  + (size_t)B * NCAND * CATTR;     // [B, 2048] indices as float
    float* keepf = topf + (size_t)B * TOPK;              // [B, 2048] 0/1 as float

    // workspace layout
    float*  gx1 = (float*)d_ws;
    float*  gy1 = gx1 + B * TOPK;
    float*  gx2 = gy1 + B * TOPK;
    float*  gy2 = gx2 + B * TOPK;
    float*  gar = gy2 + B * TOPK;
    uint32* gcv = (uint32*)(gar + B * TOPK);
    uint32* rowmask = gcv + B * TOPK;                    // 16*2048*64 u32 = 8 MiB
    uint32* vwords  = rowmask + (size_t)B * TOPK * NWORD; // B*64 u32 = 4 KiB

    int total = B * NCAND;
    decode_kernel<<<(total + 255) / 256, 256, 0, stream>>>(inp, anchors, out);
    sort_kernel<<<B, 1024, 0, stream>>>(out, topf);
    geo_kernel<<<(B * TOPK + 255) / 256, 256, 0, stream>>>(out, topf, gx1, gy1, gx2, gy2, gar, gcv, vwords);
    build_kernel<<<dim3(TOPK / 64, B), 1024, 0, stream>>>(gx1, gy1, gx2, gy2, gar, gcv, rowmask);
    scan_kernel<<<B, 512, 0, stream>>>(rowmask, vwords, keepf);
}

// Round 4
// 266.825 us; speedup vs baseline: 9.3376x; 1.1540x over previous
//
#include <hip/hip_runtime.h>

#pragma clang fp contract(off)

#define B 16
#define A 3
#define HGT 52
#define WID 52
#define HW 2704
#define NCAND 8112   // A*HW
#define CATTR 25
#define TOPK 2048
#define SORTN 8192
#define NWORD 64     // 64 words x 32 bits = 2048 cols
#define CH 64        // rows per scan chunk
#define NCHUNK (TOPK / CH)
#define EPT 8        // sort: elements per thread

typedef unsigned int uint32;
typedef unsigned long long u64;

// ---------------- decode ----------------
__global__ void decode_kernel(const float* __restrict__ inp,
                              const float* __restrict__ anchors,
                              float* __restrict__ out,
                              float* __restrict__ cws) {
    int t = blockIdx.x * blockDim.x + threadIdx.x;
    if (t >= B * NCAND) return;
    int b  = t / NCAND;
    int n  = t - b * NCAND;
    int a  = n / HW;
    int hw = n - a * HW;
    int gy = hw / WID;
    int gx = hw - gy * WID;
    const float* ip = inp + ((size_t)(b * (A * CATTR) + a * CATTR)) * HW + hw;
    float* op = out + (size_t)t * CATTR;

    float p0 = ip[0 * HW], p1 = ip[1 * HW], p2 = ip[2 * HW], p3 = ip[3 * HW], p4 = ip[4 * HW];
    float sx = 1.0f / (1.0f + expf(-p0));
    float sy = 1.0f / (1.0f + expf(-p1));
    float bx = (sx + (float)gx) * 8.0f;   // stride = 8 exactly
    float by = (sy + (float)gy) * 8.0f;
    float bw = expf(p2) * anchors[a * 2 + 0];   // (anchor/8)*8 exact
    float bh = expf(p3) * anchors[a * 2 + 1];
    float cf = 1.0f / (1.0f + expf(-p4));
    op[0] = bx; op[1] = by; op[2] = bw; op[3] = bh; op[4] = cf;
    cws[t] = cf;   // contiguous conf for the sort
#pragma unroll
    for (int c = 0; c < 20; ++c) {
        float v = ip[(5 + c) * HW];
        op[5 + c] = 1.0f / (1.0f + expf(-v));
    }
}

// ---------------- top-k: register-resident bitonic sort ----------------
// 1024 thr/block, 8 u64 keys/thread (contiguous chunk). Partner distance j:
//   j<=4   : in-register compare-exchange (no barrier)
//   8..256 : partner lane = l ^ (j/8) within wave -> __shfl_xor (no barrier)
//   >=512  : cross-wave -> LDS ping-pong mailbox, ONE barrier per pass
// key = (~(conf_bits|sign) << 32) | idx ; ascending == conf desc, idx asc.
__device__ __forceinline__ void cexd(u64& a, u64& b, bool up) {
    if ((a > b) == up) { u64 tmp = a; a = b; b = tmp; }
}

__global__ __launch_bounds__(1024) void sort_kernel(const float* __restrict__ conf,
                                                    float* __restrict__ topf) {
    extern __shared__ u64 mbox[];   // 2 x SORTN u64 = 128 KiB
    int b = blockIdx.x;
    int t = threadIdx.x;
    int base = t * EPT;

    u64 key[EPT];
    if (base + EPT <= NCAND) {
        const float4* cp4 = (const float4*)(conf + b * NCAND);
        float4 c0 = cp4[t * 2], c1 = cp4[t * 2 + 1];
        float cf[EPT] = {c0.x, c0.y, c0.z, c0.w, c1.x, c1.y, c1.z, c1.w};
#pragma unroll
        for (int e = 0; e < EPT; ++e) {
            unsigned bits = __float_as_uint(cf[e]) | 0x80000000u;
            key[e] = ((u64)(~bits) << 32) | (unsigned)(base + e);
        }
    } else {
#pragma unroll
        for (int e = 0; e < EPT; ++e) key[e] = ~0ull;   // pad sorts last
    }

    // stages k=2,4,8: fully in-thread
    cexd(key[0], key[1], true); cexd(key[2], key[3], false);
    cexd(key[4], key[5], true); cexd(key[6], key[7], false);

    cexd(key[0], key[2], true);  cexd(key[1], key[3], true);
    cexd(key[4], key[6], false); cexd(key[5], key[7], false);
    cexd(key[0], key[1], true);  cexd(key[2], key[3], true);
    cexd(key[4], key[5], false); cexd(key[6], key[7], false);

    bool up8 = ((t & 1) == 0);
    cexd(key[0], key[4], up8); cexd(key[1], key[5], up8);
    cexd(key[2], key[6], up8); cexd(key[3], key[7], up8);
    cexd(key[0], key[2], up8); cexd(key[1], key[3], up8);
    cexd(key[4], key[6], up8); cexd(key[5], key[7], up8);
    cexd(key[0], key[1], up8); cexd(key[2], key[3], up8);
    cexd(key[4], key[5], up8); cexd(key[6], key[7], up8);

    int pg = 0;
    for (unsigned k = 16; k <= SORTN; k <<= 1) {
        bool up = (((unsigned)base & k) == 0);   // uniform per thread for k>=16
        for (unsigned j = k >> 1; j >= 8; j >>= 1) {
            unsigned m = j >> 3;   // partner thread distance
            bool lower = ((t & m) == 0);
            bool kmin = (up == lower);
            if (j >= 512) {        // cross-wave: LDS mailbox
                u64* wb = mbox + (size_t)pg * SORTN;
                pg ^= 1;
#pragma unroll
                for (int e = 0; e < EPT; ++e) wb[base + e] = key[e];
                __syncthreads();
                int pbase = (t ^ m) * EPT;
#pragma unroll
                for (int e = 0; e < EPT; ++e) {
                    u64 o = wb[pbase + e];
                    key[e] = kmin ? (key[e] < o ? key[e] : o)
                                  : (key[e] > o ? key[e] : o);
                }
            } else {               // same-wave: shuffle
#pragma unroll
                for (int e = 0; e < EPT; ++e) {
                    u64 o = __shfl_xor(key[e], (int)m);
                    key[e] = kmin ? (key[e] < o ? key[e] : o)
                                  : (key[e] > o ? key[e] : o);
                }
            }
        }
        // tail j=4,2,1 in registers (direction uniform: up)
        cexd(key[0], key[4], up); cexd(key[1], key[5], up);
        cexd(key[2], key[6], up); cexd(key[3], key[7], up);
        cexd(key[0], key[2], up); cexd(key[1], key[3], up);
        cexd(key[4], key[6], up); cexd(key[5], key[7], up);
        cexd(key[0], key[1], up); cexd(key[2], key[3], up);
        cexd(key[4], key[5], up); cexd(key[6], key[7], up);
    }

    if (base < TOPK) {
#pragma unroll
        for (int e = 0; e < EPT; ++e)
            topf[(size_t)b * TOPK + base + e] = (float)(unsigned)(key[e] & 0xFFFFFFFFu);
    }
}

// ---------------- NMS stage 1: per-candidate geometry + valid-bit pack ----
__global__ __launch_bounds__(256) void geo_kernel(const float* __restrict__ out,
                                                  const float* __restrict__ topf,
                                                  float* __restrict__ gx1,
                                                  float* __restrict__ gy1,
                                                  float* __restrict__ gx2,
                                                  float* __restrict__ gy2,
                                                  float* __restrict__ gar,
                                                  uint32* __restrict__ gcv,
                                                  uint32* __restrict__ vwords) {
    int t = blockIdx.x * blockDim.x + threadIdx.x;
    if (t >= B * TOPK) return;
    int b = t >> 11;            // /2048
    int r = t & (TOPK - 1);
    int idx = (int)topf[(size_t)b * TOPK + r];
    const float* p = out + ((size_t)b * NCAND + idx) * CATTR;
    float cx = p[0], cy = p[1], w = p[2], h = p[3], cf = p[4];
    float hw_ = w * 0.5f, hh_ = h * 0.5f;  // w/2 exact
    float x1 = cx - hw_, y1 = cy - hh_, x2 = cx + hw_, y2 = cy + hh_;
    gx1[t] = x1; gy1[t] = y1; gx2[t] = x2; gy2[t] = y2;
    gar[t] = ((x2 - x1) + 1.0f) * ((y2 - y1) + 1.0f);
    float best = p[5]; int bc = 0;
#pragma unroll
    for (int c = 1; c < 20; ++c) {       // first-max argmax (numpy semantics)
        float v = p[5 + c];
        if (v > best) { best = v; bc = c; }
    }
    bool valid = (cf >= 0.5f);
    gcv[t] = (uint32)bc | (valid ? 0x100u : 0u);
    unsigned long long bal = __ballot(valid);   // t is wave-aligned (grid % 64 == 0)
    if ((t & 63) == 0) {
        vwords[(t >> 5) + 0] = (uint32)bal;
        vwords[(t >> 5) + 1] = (uint32)(bal >> 32);
    }
}

// ---------------- NMS stage 2: suppression bitmask build ----------------
__global__ __launch_bounds__(1024) void build_kernel(const float* __restrict__ gx1,
                                                     const float* __restrict__ gy1,
                                                     const float* __restrict__ gx2,
                                                     const float* __restrict__ gy2,
                                                     const float* __restrict__ gar,
                                                     const uint32* __restrict__ gcv,
                                                     uint32* __restrict__ rowmask) {
    __shared__ float4 x4s[TOPK];    // 32 KiB
    __shared__ float  ars[TOPK];    // 8 KiB
    __shared__ uint32 clss[TOPK];   // 8 KiB
    int bt  = blockIdx.y;
    int tid = threadIdx.x;
    int base = bt * TOPK;

    for (int s = tid; s < TOPK; s += 1024) {
        int j = (s & 63) * 32 + (s >> 6);   // inverse swizzle
        int g = base + j;
        x4s[s]  = make_float4(gx1[g], gy1[g], gx2[g], gy2[g]);
        ars[s]  = gar[g];
        clss[s] = gcv[g] & 0xffu;
    }
    __syncthreads();

    int w  = tid & 63;
    int rg = tid >> 6;
    int i0 = blockIdx.x * 64 + rg * 4;

    float rx1[4], ry1[4], rx2[4], ry2[4], rar[4];
    uint32 rcl[4];
#pragma unroll
    for (int r = 0; r < 4; ++r) {
        int g = base + i0 + r;
        rx1[r] = gx1[g]; ry1[r] = gy1[g]; rx2[r] = gx2[g]; ry2[r] = gy2[g];
        rar[r] = gar[g]; rcl[r] = gcv[g] & 0xffu;
    }
    uint32 word[4] = {0u, 0u, 0u, 0u};

    for (int b2 = 0; b2 < 32; ++b2) {
        int sidx = b2 * 64 + w;
        float4 c  = x4s[sidx];
        float car = ars[sidx];
        uint32 cc = clss[sidx];
#pragma unroll
        for (int r = 0; r < 4; ++r) {
            float ix1 = fmaxf(rx1[r], c.x);
            float iy1 = fmaxf(ry1[r], c.y);
            float ix2 = fminf(rx2[r], c.z);
            float iy2 = fminf(ry2[r], c.w);
            float iw = fmaxf((ix2 - ix1) + 1.0f, 0.0f);
            float ih = fmaxf((iy2 - iy1) + 1.0f, 0.0f);
            float inter = iw * ih;
            float iou = inter / (((rar[r] + car) - inter) + 1e-16f);
            if ((iou >= 0.4f) && (cc == rcl[r])) word[r] |= 1u << b2;
        }
    }
#pragma unroll
    for (int r = 0; r < 4; ++r) {
        rowmask[((size_t)(base + i0 + r)) * NWORD + w] = word[r];
    }
}

// ---------------- NMS stage 3: serial greedy scan via LDS streaming -------
#define SPF 8
__global__ __launch_bounds__(512) void scan_kernel(const uint32* __restrict__ rowmask,
                                                   const uint32* __restrict__ vwords,
                                                   float* __restrict__ keepf) {
    __shared__ uint32 buf[2][CH * NWORD];   // 2 x 16 KiB
    int bt  = blockIdx.x;
    int tid = threadIdx.x;
    int wv  = tid >> 6;
    int l   = tid & 63;
    const uint32* rm = rowmask + (size_t)bt * TOPK * NWORD;

    if (wv > 0) {
        int ctid = tid - 64;
        const uint4* src = (const uint4*)rm;
        uint4* dst = (uint4*)buf[0];
        for (int o = ctid; o < CH * NWORD / 4; o += 448) dst[o] = src[o];
    }
    uint32 vw = 0, supp = 0, keepw = 0, cur = 0, vcur = 0;
    if (wv == 0) vw = vwords[bt * 64 + l];
    __syncthreads();

    for (int c = 0; c < NCHUNK; ++c) {
        if (wv > 0) {
            if (c + 1 < NCHUNK) {
                int ctid = tid - 64;
                const uint4* src = (const uint4*)(rm + (size_t)(c + 1) * CH * NWORD);
                uint4* dst = (uint4*)buf[(c + 1) & 1];
                for (int o = ctid; o < CH * NWORD / 4; o += 448) dst[o] = src[o];
            }
        } else {
            const uint32* bp = buf[c & 1];
            uint32 rlb[SPF], rwb[SPF];
#pragma unroll
            for (int k = 0; k < SPF; ++k) {
                rlb[k] = bp[k * NWORD + l];
                rwb[k] = bp[k * NWORD + ((c * CH + k) >> 5)];
            }
            for (int kk = 0; kk < CH; kk += SPF) {
#pragma unroll
                for (int k2 = 0; k2 < SPF; ++k2) {
                    int k = kk + k2;
                    int i = c * CH + k;
                    uint32 rl = rlb[k2], rw = rwb[k2];
                    int nk = k + SPF;
                    if (nk < CH) {
                        rlb[k2] = bp[nk * NWORD + l];
                        rwb[k2] = bp[nk * NWORD + ((c * CH + nk) >> 5)];
                    }
                    int b2 = i & 31;
                    if (b2 == 0) {
                        cur  = __shfl(supp, i >> 5);
                        vcur = __shfl(vw,   i >> 5);
                    }
                    uint32 kf = ((vcur >> b2) & ~(cur >> b2)) & 1u;
                    uint32 m = (uint32)(-(int)kf);
                    cur  |= rw & m;
                    supp |= rl & m;
                    if (l == (i >> 5)) keepw |= kf << b2;
                }
            }
        }
        __syncthreads();
    }

    if (wv == 0) {
#pragma unroll
        for (int k = 0; k < 32; ++k)
            keepf[bt * TOPK + l * 32 + k] = (float)((keepw >> k) & 1u);
    }
}

extern "C" void kernel_launch(void* const* d_in, const int* in_sizes, int n_in,
                              void* d_out, int out_size, void* d_ws, size_t ws_size,
                              hipStream_t stream) {
    const float* inp     = (const float*)d_in[0];
    const float* anchors = (const float*)d_in[1];
    float* out   = (float*)d_out;                        // [B, N, 25]
    float* topf  = out  + (size_t)B * NCAND * CATTR;     // [B, 2048] indices as float
    float* keepf = topf + (size_t)B * TOPK;              // [B, 2048] 0/1 as float

    // workspace layout
    float*  cws = (float*)d_ws;                          // [B, NCAND] conf
    float*  gx1 = cws + B * NCAND;
    float*  gy1 = gx1 + B * TOPK;
    float*  gx2 = gy1 + B * TOPK;
    float*  gy2 = gx2 + B * TOPK;
    float*  gar = gy2 + B * TOPK;
    uint32* gcv = (uint32*)(gar + B * TOPK);
    uint32* rowmask = gcv + B * TOPK;                    // 16*2048*64 u32 = 8 MiB
    uint32* vwords  = rowmask + (size_t)B * TOPK * NWORD;

    int total = B * NCAND;
    decode_kernel<<<(total + 255) / 256, 256, 0, stream>>>(inp, anchors, out, cws);
    sort_kernel<<<B, 1024, 2 * SORTN * sizeof(u64), stream>>>(cws, topf);
    geo_kernel<<<(B * TOPK + 255) / 256, 256, 0, stream>>>(out, topf, gx1, gy1, gx2, gy2, gar, gcv, vwords);
    build_kernel<<<dim3(TOPK / 64, B), 1024, 0, stream>>>(gx1, gy1, gx2, gy2, gar, gcv, rowmask);
    scan_kernel<<<B, 512, 0, stream>>>(rowmask, vwords, keepf);
}

// Round 5
// 225.565 us; speedup vs baseline: 11.0456x; 1.1829x over previous
//
#include <hip/hip_runtime.h>

#pragma clang fp contract(off)

#define B 16
#define A 3
#define HGT 52
#define WID 52
#define HW 2704
#define NCAND 8112   // A*HW
#define CATTR 25
#define TOPK 2048
#define NWORD 64     // 64 words x 32 bits = 2048 cols
#define CH 64        // rows per scan chunk
#define NCHUNK (TOPK / CH)
#define EPT 8        // sort: elements per thread

typedef unsigned int uint32;
typedef unsigned long long u64;

// ---------------- decode ----------------
__global__ void decode_kernel(const float* __restrict__ inp,
                              const float* __restrict__ anchors,
                              float* __restrict__ out,
                              float* __restrict__ cws) {
    int t = blockIdx.x * blockDim.x + threadIdx.x;
    if (t >= B * NCAND) return;
    int b  = t / NCAND;
    int n  = t - b * NCAND;
    int a  = n / HW;
    int hw = n - a * HW;
    int gy = hw / WID;
    int gx = hw - gy * WID;
    const float* ip = inp + ((size_t)(b * (A * CATTR) + a * CATTR)) * HW + hw;
    float* op = out + (size_t)t * CATTR;

    float p0 = ip[0 * HW], p1 = ip[1 * HW], p2 = ip[2 * HW], p3 = ip[3 * HW], p4 = ip[4 * HW];
    float sx = 1.0f / (1.0f + expf(-p0));
    float sy = 1.0f / (1.0f + expf(-p1));
    float bx = (sx + (float)gx) * 8.0f;   // stride = 8 exactly
    float by = (sy + (float)gy) * 8.0f;
    float bw = expf(p2) * anchors[a * 2 + 0];   // (anchor/8)*8 exact
    float bh = expf(p3) * anchors[a * 2 + 1];
    float cf = 1.0f / (1.0f + expf(-p4));
    op[0] = bx; op[1] = by; op[2] = bw; op[3] = bh; op[4] = cf;
    cws[t] = cf;   // contiguous conf for the sort
#pragma unroll
    for (int c = 0; c < 20; ++c) {
        float v = ip[(5 + c) * HW];
        op[5 + c] = 1.0f / (1.0f + expf(-v));
    }
}

// ---------------- sort helpers ----------------
// key = (~(conf_bits|sign) << 32) | idx ; ascending == conf desc, idx asc.
__device__ __forceinline__ void cexd(u64& a, u64& b, bool up) {
    if ((a > b) == up) { u64 tmp = a; a = b; b = tmp; }
}

// exchange-and-select for cross-thread passes
__device__ __forceinline__ u64 sel(u64 k, u64 o, bool kmin) {
    return kmin ? (k < o ? k : o) : (k > o ? k : o);
}

// bitonic merge of a 2048-element bitonic sequence to ascending order.
// 256 threads x EPT=8 regs; mb = 2048-u64 LDS mailbox in SoA layout
// (mb[e*256+t]: lanes 8B apart -> 2-way bank alias -> conflict-free).
__device__ __forceinline__ void bitonic_merge_2048(u64 key[EPT], u64* mb, int t) {
    for (unsigned j = 1024; j >= 8; j >>= 1) {
        unsigned m = j >> 3;
        bool kmin = ((t & m) == 0);
        if (m >= 64) {
            __syncthreads();
#pragma unroll
            for (int e = 0; e < EPT; ++e) mb[e * 256 + t] = key[e];
            __syncthreads();
            int pt = t ^ (int)m;
#pragma unroll
            for (int e = 0; e < EPT; ++e) key[e] = sel(key[e], mb[e * 256 + pt], kmin);
        } else {
#pragma unroll
            for (int e = 0; e < EPT; ++e) {
                u64 o = __shfl_xor(key[e], (int)m);
                key[e] = sel(key[e], o, kmin);
            }
        }
    }
    cexd(key[0], key[4], true); cexd(key[1], key[5], true);
    cexd(key[2], key[6], true); cexd(key[3], key[7], true);
    cexd(key[0], key[2], true); cexd(key[1], key[3], true);
    cexd(key[4], key[6], true); cexd(key[5], key[7], true);
    cexd(key[0], key[1], true); cexd(key[2], key[3], true);
    cexd(key[4], key[5], true); cexd(key[6], key[7], true);
}

// ---------------- S1: sort each 2048-chunk ascending ----------------
// grid 64 (4 chunks x 16 batches), 256 thr, 8 keys/thr.
__global__ __launch_bounds__(256) void sort1_kernel(const float* __restrict__ conf,
                                                    u64* __restrict__ runs) {
    __shared__ u64 mb[2048];   // 16 KiB SoA mailbox
    int blk = blockIdx.x;
    int b = blk >> 2, c = blk & 3;
    int t = threadIdx.x;
    int base = t * EPT;               // local 0..2047
    int gbase = c * 2048 + base;      // candidate index in batch
    const float* cp = conf + b * NCAND;

    u64 key[EPT];
    if (gbase + EPT <= NCAND) {
        const float4* cp4 = (const float4*)(cp + gbase);   // 32B-aligned
        float4 c0 = cp4[0], c1 = cp4[1];
        float cf[EPT] = {c0.x, c0.y, c0.z, c0.w, c1.x, c1.y, c1.z, c1.w};
#pragma unroll
        for (int e = 0; e < EPT; ++e) {
            unsigned bits = __float_as_uint(cf[e]) | 0x80000000u;
            key[e] = ((u64)(~bits) << 32) | (unsigned)(gbase + e);
        }
    } else {
#pragma unroll
        for (int e = 0; e < EPT; ++e) {
            int idx = gbase + e;
            if (idx < NCAND) {
                unsigned bits = __float_as_uint(cp[idx]) | 0x80000000u;
                key[e] = ((u64)(~bits) << 32) | (unsigned)idx;
            } else key[e] = ~0ull;   // pad sorts last
        }
    }

    // stages k=2,4,8 fully in-thread
    cexd(key[0], key[1], true); cexd(key[2], key[3], false);
    cexd(key[4], key[5], true); cexd(key[6], key[7], false);

    cexd(key[0], key[2], true);  cexd(key[1], key[3], true);
    cexd(key[4], key[6], false); cexd(key[5], key[7], false);
    cexd(key[0], key[1], true);  cexd(key[2], key[3], true);
    cexd(key[4], key[5], false); cexd(key[6], key[7], false);

    bool up8 = ((t & 1) == 0);
    cexd(key[0], key[4], up8); cexd(key[1], key[5], up8);
    cexd(key[2], key[6], up8); cexd(key[3], key[7], up8);
    cexd(key[0], key[2], up8); cexd(key[1], key[3], up8);
    cexd(key[4], key[6], up8); cexd(key[5], key[7], up8);
    cexd(key[0], key[1], up8); cexd(key[2], key[3], up8);
    cexd(key[4], key[5], up8); cexd(key[6], key[7], up8);

    for (unsigned k = 16; k <= 2048; k <<= 1) {
        bool up = (((unsigned)base & k) == 0);
        for (unsigned j = k >> 1; j >= 8; j >>= 1) {
            unsigned m = j >> 3;
            bool kmin = (up == ((t & m) == 0));
            if (m >= 64) {
                __syncthreads();
#pragma unroll
                for (int e = 0; e < EPT; ++e) mb[e * 256 + t] = key[e];
                __syncthreads();
                int pt = t ^ (int)m;
#pragma unroll
                for (int e = 0; e < EPT; ++e) key[e] = sel(key[e], mb[e * 256 + pt], kmin);
            } else {
#pragma unroll
                for (int e = 0; e < EPT; ++e) {
                    u64 o = __shfl_xor(key[e], (int)m);
                    key[e] = sel(key[e], o, kmin);
                }
            }
        }
        cexd(key[0], key[4], up); cexd(key[1], key[5], up);
        cexd(key[2], key[6], up); cexd(key[3], key[7], up);
        cexd(key[0], key[2], up); cexd(key[1], key[3], up);
        cexd(key[4], key[6], up); cexd(key[5], key[7], up);
        cexd(key[0], key[1], up); cexd(key[2], key[3], up);
        cexd(key[4], key[5], up); cexd(key[6], key[7], up);
    }

    u64* R = runs + ((size_t)b * 4 + c) * 2048;
#pragma unroll
    for (int e = 0; e < EPT; ++e) R[base + e] = key[e];
}

// ---------------- S2: merge+prune two 2048-runs -> sorted top-2048 -------
// c[i] = min(A[i], B[2047-i]) is the lower half of the j=2048 bitonic
// exchange: contains the 2048 smallest keys of the union, and is bitonic.
__global__ __launch_bounds__(256) void sort2_kernel(const u64* __restrict__ runs,
                                                    u64* __restrict__ half) {
    __shared__ u64 mb[2048];
    int blk = blockIdx.x;
    int b = blk >> 1, p = blk & 1;
    int t = threadIdx.x;
    int base = t * EPT;
    const u64* Av = runs + ((size_t)b * 4 + p * 2) * 2048;
    const u64* Bv = Av + 2048;

    u64 key[EPT];
#pragma unroll
    for (int e = 0; e < EPT; ++e) {
        u64 a = Av[base + e];
        u64 o = Bv[2047 - (base + e)];
        key[e] = a < o ? a : o;
    }
    bitonic_merge_2048(key, mb, t);
    u64* H = half + ((size_t)b * 2 + p) * 2048;
#pragma unroll
    for (int e = 0; e < EPT; ++e) H[base + e] = key[e];
}

// ---------------- S3: final merge+prune -> topf ----------------
__global__ __launch_bounds__(256) void sort3_kernel(const u64* __restrict__ half,
                                                    float* __restrict__ topf) {
    __shared__ u64 mb[2048];
    int b = blockIdx.x;
    int t = threadIdx.x;
    int base = t * EPT;
    const u64* Av = half + (size_t)b * 2 * 2048;
    const u64* Bv = Av + 2048;

    u64 key[EPT];
#pragma unroll
    for (int e = 0; e < EPT; ++e) {
        u64 a = Av[base + e];
        u64 o = Bv[2047 - (base + e)];
        key[e] = a < o ? a : o;
    }
    bitonic_merge_2048(key, mb, t);
#pragma unroll
    for (int e = 0; e < EPT; ++e)
        topf[(size_t)b * TOPK + base + e] = (float)(unsigned)(key[e] & 0xFFFFFFFFu);
}

// ---------------- NMS stage 1: per-candidate geometry + valid-bit pack ----
__global__ __launch_bounds__(256) void geo_kernel(const float* __restrict__ out,
                                                  const float* __restrict__ topf,
                                                  float* __restrict__ gx1,
                                                  float* __restrict__ gy1,
                                                  float* __restrict__ gx2,
                                                  float* __restrict__ gy2,
                                                  float* __restrict__ gar,
                                                  uint32* __restrict__ gcv,
                                                  uint32* __restrict__ vwords) {
    int t = blockIdx.x * blockDim.x + threadIdx.x;
    if (t >= B * TOPK) return;
    int b = t >> 11;            // /2048
    int r = t & (TOPK - 1);
    int idx = (int)topf[(size_t)b * TOPK + r];
    const float* p = out + ((size_t)b * NCAND + idx) * CATTR;
    float cx = p[0], cy = p[1], w = p[2], h = p[3], cf = p[4];
    float hw_ = w * 0.5f, hh_ = h * 0.5f;  // w/2 exact
    float x1 = cx - hw_, y1 = cy - hh_, x2 = cx + hw_, y2 = cy + hh_;
    gx1[t] = x1; gy1[t] = y1; gx2[t] = x2; gy2[t] = y2;
    gar[t] = ((x2 - x1) + 1.0f) * ((y2 - y1) + 1.0f);
    float best = p[5]; int bc = 0;
#pragma unroll
    for (int c = 1; c < 20; ++c) {       // first-max argmax (numpy semantics)
        float v = p[5 + c];
        if (v > best) { best = v; bc = c; }
    }
    bool valid = (cf >= 0.5f);
    gcv[t] = (uint32)bc | (valid ? 0x100u : 0u);
    unsigned long long bal = __ballot(valid);   // t is wave-aligned
    if ((t & 63) == 0) {
        vwords[(t >> 5) + 0] = (uint32)bal;
        vwords[(t >> 5) + 1] = (uint32)(bal >> 32);
    }
}

// ---------------- NMS stage 2: suppression bitmask build ----------------
__global__ __launch_bounds__(1024) void build_kernel(const float* __restrict__ gx1,
                                                     const float* __restrict__ gy1,
                                                     const float* __restrict__ gx2,
                                                     const float* __restrict__ gy2,
                                                     const float* __restrict__ gar,
                                                     const uint32* __restrict__ gcv,
                                                     uint32* __restrict__ rowmask) {
    __shared__ float4 x4s[TOPK];    // 32 KiB
    __shared__ float  ars[TOPK];    // 8 KiB
    __shared__ uint32 clss[TOPK];   // 8 KiB
    int bt  = blockIdx.y;
    int tid = threadIdx.x;
    int base = bt * TOPK;

    for (int s = tid; s < TOPK; s += 1024) {
        int j = (s & 63) * 32 + (s >> 6);   // inverse swizzle
        int g = base + j;
        x4s[s]  = make_float4(gx1[g], gy1[g], gx2[g], gy2[g]);
        ars[s]  = gar[g];
        clss[s] = gcv[g] & 0xffu;
    }
    __syncthreads();

    int w  = tid & 63;
    int rg = tid >> 6;
    int i0 = blockIdx.x * 64 + rg * 4;

    float rx1[4], ry1[4], rx2[4], ry2[4], rar[4];
    uint32 rcl[4];
#pragma unroll
    for (int r = 0; r < 4; ++r) {
        int g = base + i0 + r;
        rx1[r] = gx1[g]; ry1[r] = gy1[g]; rx2[r] = gx2[g]; ry2[r] = gy2[g];
        rar[r] = gar[g]; rcl[r] = gcv[g] & 0xffu;
    }
    uint32 word[4] = {0u, 0u, 0u, 0u};

    for (int b2 = 0; b2 < 32; ++b2) {
        int sidx = b2 * 64 + w;
        float4 c  = x4s[sidx];
        float car = ars[sidx];
        uint32 cc = clss[sidx];
#pragma unroll
        for (int r = 0; r < 4; ++r) {
            float ix1 = fmaxf(rx1[r], c.x);
            float iy1 = fmaxf(ry1[r], c.y);
            float ix2 = fminf(rx2[r], c.z);
            float iy2 = fminf(ry2[r], c.w);
            float iw = fmaxf((ix2 - ix1) + 1.0f, 0.0f);
            float ih = fmaxf((iy2 - iy1) + 1.0f, 0.0f);
            float inter = iw * ih;
            float iou = inter / (((rar[r] + car) - inter) + 1e-16f);
            if ((iou >= 0.4f) && (cc == rcl[r])) word[r] |= 1u << b2;
        }
    }
#pragma unroll
    for (int r = 0; r < 4; ++r) {
        rowmask[((size_t)(base + i0 + r)) * NWORD + w] = word[r];
    }
}

// ---------------- NMS stage 3: serial greedy scan via LDS streaming -------
#define SPF 8
__global__ __launch_bounds__(512) void scan_kernel(const uint32* __restrict__ rowmask,
                                                   const uint32* __restrict__ vwords,
                                                   float* __restrict__ keepf) {
    __shared__ uint32 buf[2][CH * NWORD];   // 2 x 16 KiB
    int bt  = blockIdx.x;
    int tid = threadIdx.x;
    int wv  = tid >> 6;
    int l   = tid & 63;
    const uint32* rm = rowmask + (size_t)bt * TOPK * NWORD;

    if (wv > 0) {
        int ctid = tid - 64;
        const uint4* src = (const uint4*)rm;
        uint4* dst = (uint4*)buf[0];
        for (int o = ctid; o < CH * NWORD / 4; o += 448) dst[o] = src[o];
    }
    uint32 vw = 0, supp = 0, keepw = 0, cur = 0, vcur = 0;
    if (wv == 0) vw = vwords[bt * 64 + l];
    __syncthreads();

    for (int c = 0; c < NCHUNK; ++c) {
        if (wv > 0) {
            if (c + 1 < NCHUNK) {
                int ctid = tid - 64;
                const uint4* src = (const uint4*)(rm + (size_t)(c + 1) * CH * NWORD);
                uint4* dst = (uint4*)buf[(c + 1) & 1];
                for (int o = ctid; o < CH * NWORD / 4; o += 448) dst[o] = src[o];
            }
        } else {
            const uint32* bp = buf[c & 1];
            uint32 rlb[SPF], rwb[SPF];
#pragma unroll
            for (int k = 0; k < SPF; ++k) {
                rlb[k] = bp[k * NWORD + l];
                rwb[k] = bp[k * NWORD + ((c * CH + k) >> 5)];
            }
            for (int kk = 0; kk < CH; kk += SPF) {
#pragma unroll
                for (int k2 = 0; k2 < SPF; ++k2) {
                    int k = kk + k2;
                    int i = c * CH + k;
                    uint32 rl = rlb[k2], rw = rwb[k2];
                    int nk = k + SPF;
                    if (nk < CH) {
                        rlb[k2] = bp[nk * NWORD + l];
                        rwb[k2] = bp[nk * NWORD + ((c * CH + nk) >> 5)];
                    }
                    int b2 = i & 31;
                    if (b2 == 0) {
                        cur  = __shfl(supp, i >> 5);
                        vcur = __shfl(vw,   i >> 5);
                    }
                    uint32 kf = ((vcur >> b2) & ~(cur >> b2)) & 1u;
                    uint32 m = (uint32)(-(int)kf);
                    cur  |= rw & m;
                    supp |= rl & m;
                    if (l == (i >> 5)) keepw |= kf << b2;
                }
            }
        }
        __syncthreads();
    }

    if (wv == 0) {
#pragma unroll
        for (int k = 0; k < 32; ++k)
            keepf[bt * TOPK + l * 32 + k] = (float)((keepw >> k) & 1u);
    }
}

extern "C" void kernel_launch(void* const* d_in, const int* in_sizes, int n_in,
                              void* d_out, int out_size, void* d_ws, size_t ws_size,
                              hipStream_t stream) {
    const float* inp     = (const float*)d_in[0];
    const float* anchors = (const float*)d_in[1];
    float* out   = (float*)d_out;                        // [B, N, 25]
    float* topf  = out  + (size_t)B * NCAND * CATTR;     // [B, 2048] indices as float
    float* keepf = topf + (size_t)B * TOPK;              // [B, 2048] 0/1 as float

    // workspace layout
    float*  cws = (float*)d_ws;                          // [B, NCAND] conf
    float*  gx1 = cws + B * NCAND;
    float*  gy1 = gx1 + B * TOPK;
    float*  gx2 = gy1 + B * TOPK;
    float*  gy2 = gx2 + B * TOPK;
    float*  gar = gy2 + B * TOPK;
    uint32* gcv = (uint32*)(gar + B * TOPK);
    uint32* rowmask = gcv + B * TOPK;                    // 16*2048*64 u32 = 8 MiB
    uint32* vwords  = rowmask + (size_t)B * TOPK * NWORD;
    // sort scratch aliases onto rowmask: sort (S1-S3) completes before
    // build_kernel writes rowmask (same-stream ordering).
    u64* runs = (u64*)rowmask;                           // B*4*2048 u64 = 1 MiB
    u64* half = runs + (size_t)B * 4 * 2048;             // B*2*2048 u64 = 0.5 MiB

    int total = B * NCAND;
    decode_kernel<<<(total + 255) / 256, 256, 0, stream>>>(inp, anchors, out, cws);
    sort1_kernel<<<B * 4, 256, 0, stream>>>(cws, runs);
    sort2_kernel<<<B * 2, 256, 0, stream>>>(runs, half);
    sort3_kernel<<<B, 256, 0, stream>>>(half, topf);
    geo_kernel<<<(B * TOPK + 255) / 256, 256, 0, stream>>>(out, topf, gx1, gy1, gx2, gy2, gar, gcv, vwords);
    build_kernel<<<dim3(TOPK / 64, B), 1024, 0, stream>>>(gx1, gy1, gx2, gy2, gar, gcv, rowmask);
    scan_kernel<<<B, 512, 0, stream>>>(rowmask, vwords, keepf);
}

// Round 6
// 206.481 us; speedup vs baseline: 12.0665x; 1.0924x over previous
//
#include <hip/hip_runtime.h>

#pragma clang fp contract(off)

#define B 16
#define A 3
#define HGT 52
#define WID 52
#define HW 2704
#define NCAND 8112   // A*HW
#define CATTR 25
#define TOPK 2048
#define NWORD 64     // 64 u32 words x 32 bits = 2048 cols
#define CH 128       // rows per scan chunk
#define NCHUNK (TOPK / CH)
#define EPT 8        // sort: elements per thread

typedef unsigned int uint32;
typedef unsigned long long u64;

// ---------------- decode ----------------
__global__ void decode_kernel(const float* __restrict__ inp,
                              const float* __restrict__ anchors,
                              float* __restrict__ out,
                              float* __restrict__ cws) {
    int t = blockIdx.x * blockDim.x + threadIdx.x;
    if (t >= B * NCAND) return;
    int b  = t / NCAND;
    int n  = t - b * NCAND;
    int a  = n / HW;
    int hw = n - a * HW;
    int gy = hw / WID;
    int gx = hw - gy * WID;
    const float* ip = inp + ((size_t)(b * (A * CATTR) + a * CATTR)) * HW + hw;
    float* op = out + (size_t)t * CATTR;

    float p0 = ip[0 * HW], p1 = ip[1 * HW], p2 = ip[2 * HW], p3 = ip[3 * HW], p4 = ip[4 * HW];
    float sx = 1.0f / (1.0f + expf(-p0));
    float sy = 1.0f / (1.0f + expf(-p1));
    float bx = (sx + (float)gx) * 8.0f;   // stride = 8 exactly
    float by = (sy + (float)gy) * 8.0f;
    float bw = expf(p2) * anchors[a * 2 + 0];   // (anchor/8)*8 exact
    float bh = expf(p3) * anchors[a * 2 + 1];
    float cf = 1.0f / (1.0f + expf(-p4));
    op[0] = bx; op[1] = by; op[2] = bw; op[3] = bh; op[4] = cf;
    cws[t] = cf;   // contiguous conf for the sort
#pragma unroll
    for (int c = 0; c < 20; ++c) {
        float v = ip[(5 + c) * HW];
        op[5 + c] = 1.0f / (1.0f + expf(-v));
    }
}

// ---------------- sort helpers ----------------
// key = (~(conf_bits|sign) << 32) | idx ; ascending == conf desc, idx asc.
__device__ __forceinline__ void cexd(u64& a, u64& b, bool up) {
    if ((a > b) == up) { u64 tmp = a; a = b; b = tmp; }
}

__device__ __forceinline__ u64 sel(u64 k, u64 o, bool kmin) {
    return kmin ? (k < o ? k : o) : (k > o ? k : o);
}

// bitonic merge of a 2048-element bitonic sequence to ascending order.
// 256 threads x EPT=8 regs; mb = 2048-u64 LDS mailbox in SoA layout.
__device__ __forceinline__ void bitonic_merge_2048(u64 key[EPT], u64* mb, int t) {
    for (unsigned j = 1024; j >= 8; j >>= 1) {
        unsigned m = j >> 3;
        bool kmin = ((t & m) == 0);
        if (m >= 64) {
            __syncthreads();
#pragma unroll
            for (int e = 0; e < EPT; ++e) mb[e * 256 + t] = key[e];
            __syncthreads();
            int pt = t ^ (int)m;
#pragma unroll
            for (int e = 0; e < EPT; ++e) key[e] = sel(key[e], mb[e * 256 + pt], kmin);
        } else {
#pragma unroll
            for (int e = 0; e < EPT; ++e) {
                u64 o = __shfl_xor(key[e], (int)m);
                key[e] = sel(key[e], o, kmin);
            }
        }
    }
    cexd(key[0], key[4], true); cexd(key[1], key[5], true);
    cexd(key[2], key[6], true); cexd(key[3], key[7], true);
    cexd(key[0], key[2], true); cexd(key[1], key[3], true);
    cexd(key[4], key[6], true); cexd(key[5], key[7], true);
    cexd(key[0], key[1], true); cexd(key[2], key[3], true);
    cexd(key[4], key[5], true); cexd(key[6], key[7], true);
}

// ---------------- S1: sort each 2048-chunk ascending ----------------
__global__ __launch_bounds__(256) void sort1_kernel(const float* __restrict__ conf,
                                                    u64* __restrict__ runs) {
    __shared__ u64 mb[2048];   // 16 KiB SoA mailbox
    int blk = blockIdx.x;
    int b = blk >> 2, c = blk & 3;
    int t = threadIdx.x;
    int base = t * EPT;               // local 0..2047
    int gbase = c * 2048 + base;      // candidate index in batch
    const float* cp = conf + b * NCAND;

    u64 key[EPT];
    if (gbase + EPT <= NCAND) {
        const float4* cp4 = (const float4*)(cp + gbase);
        float4 c0 = cp4[0], c1 = cp4[1];
        float cf[EPT] = {c0.x, c0.y, c0.z, c0.w, c1.x, c1.y, c1.z, c1.w};
#pragma unroll
        for (int e = 0; e < EPT; ++e) {
            unsigned bits = __float_as_uint(cf[e]) | 0x80000000u;
            key[e] = ((u64)(~bits) << 32) | (unsigned)(gbase + e);
        }
    } else {
#pragma unroll
        for (int e = 0; e < EPT; ++e) {
            int idx = gbase + e;
            if (idx < NCAND) {
                unsigned bits = __float_as_uint(cp[idx]) | 0x80000000u;
                key[e] = ((u64)(~bits) << 32) | (unsigned)idx;
            } else key[e] = ~0ull;   // pad sorts last
        }
    }

    cexd(key[0], key[1], true); cexd(key[2], key[3], false);
    cexd(key[4], key[5], true); cexd(key[6], key[7], false);

    cexd(key[0], key[2], true);  cexd(key[1], key[3], true);
    cexd(key[4], key[6], false); cexd(key[5], key[7], false);
    cexd(key[0], key[1], true);  cexd(key[2], key[3], true);
    cexd(key[4], key[5], false); cexd(key[6], key[7], false);

    bool up8 = ((t & 1) == 0);
    cexd(key[0], key[4], up8); cexd(key[1], key[5], up8);
    cexd(key[2], key[6], up8); cexd(key[3], key[7], up8);
    cexd(key[0], key[2], up8); cexd(key[1], key[3], up8);
    cexd(key[4], key[6], up8); cexd(key[5], key[7], up8);
    cexd(key[0], key[1], up8); cexd(key[2], key[3], up8);
    cexd(key[4], key[5], up8); cexd(key[6], key[7], up8);

    for (unsigned k = 16; k <= 2048; k <<= 1) {
        bool up = (((unsigned)base & k) == 0);
        for (unsigned j = k >> 1; j >= 8; j >>= 1) {
            unsigned m = j >> 3;
            bool kmin = (up == ((t & m) == 0));
            if (m >= 64) {
                __syncthreads();
#pragma unroll
                for (int e = 0; e < EPT; ++e) mb[e * 256 + t] = key[e];
                __syncthreads();
                int pt = t ^ (int)m;
#pragma unroll
                for (int e = 0; e < EPT; ++e) key[e] = sel(key[e], mb[e * 256 + pt], kmin);
            } else {
#pragma unroll
                for (int e = 0; e < EPT; ++e) {
                    u64 o = __shfl_xor(key[e], (int)m);
                    key[e] = sel(key[e], o, kmin);
                }
            }
        }
        cexd(key[0], key[4], up); cexd(key[1], key[5], up);
        cexd(key[2], key[6], up); cexd(key[3], key[7], up);
        cexd(key[0], key[2], up); cexd(key[1], key[3], up);
        cexd(key[4], key[6], up); cexd(key[5], key[7], up);
        cexd(key[0], key[1], up); cexd(key[2], key[3], up);
        cexd(key[4], key[5], up); cexd(key[6], key[7], up);
    }

    u64* R = runs + ((size_t)b * 4 + c) * 2048;
#pragma unroll
    for (int e = 0; e < EPT; ++e) R[base + e] = key[e];
}

// ---------------- S2: merge+prune two 2048-runs -> sorted 2048 -------
__global__ __launch_bounds__(256) void sort2_kernel(const u64* __restrict__ runs,
                                                    u64* __restrict__ half) {
    __shared__ u64 mb[2048];
    int blk = blockIdx.x;
    int b = blk >> 1, p = blk & 1;
    int t = threadIdx.x;
    int base = t * EPT;
    const u64* Av = runs + ((size_t)b * 4 + p * 2) * 2048;
    const u64* Bv = Av + 2048;

    u64 key[EPT];
#pragma unroll
    for (int e = 0; e < EPT; ++e) {
        u64 a = Av[base + e];
        u64 o = Bv[2047 - (base + e)];
        key[e] = a < o ? a : o;
    }
    bitonic_merge_2048(key, mb, t);
    u64* H = half + ((size_t)b * 2 + p) * 2048;
#pragma unroll
    for (int e = 0; e < EPT; ++e) H[base + e] = key[e];
}

// ---------------- S3: final merge+prune -> topf ----------------
__global__ __launch_bounds__(256) void sort3_kernel(const u64* __restrict__ half,
                                                    float* __restrict__ topf) {
    __shared__ u64 mb[2048];
    int b = blockIdx.x;
    int t = threadIdx.x;
    int base = t * EPT;
    const u64* Av = half + (size_t)b * 2 * 2048;
    const u64* Bv = Av + 2048;

    u64 key[EPT];
#pragma unroll
    for (int e = 0; e < EPT; ++e) {
        u64 a = Av[base + e];
        u64 o = Bv[2047 - (base + e)];
        key[e] = a < o ? a : o;
    }
    bitonic_merge_2048(key, mb, t);
#pragma unroll
    for (int e = 0; e < EPT; ++e)
        topf[(size_t)b * TOPK + base + e] = (float)(unsigned)(key[e] & 0xFFFFFFFFu);
}

// ---------------- NMS stage 1: per-candidate geometry + valid-bit pack ----
__global__ __launch_bounds__(256) void geo_kernel(const float* __restrict__ out,
                                                  const float* __restrict__ topf,
                                                  float* __restrict__ gx1,
                                                  float* __restrict__ gy1,
                                                  float* __restrict__ gx2,
                                                  float* __restrict__ gy2,
                                                  float* __restrict__ gar,
                                                  uint32* __restrict__ gcv,
                                                  uint32* __restrict__ vwords) {
    int t = blockIdx.x * blockDim.x + threadIdx.x;
    if (t >= B * TOPK) return;
    int b = t >> 11;            // /2048
    int r = t & (TOPK - 1);
    int idx = (int)topf[(size_t)b * TOPK + r];
    const float* p = out + ((size_t)b * NCAND + idx) * CATTR;
    float cx = p[0], cy = p[1], w = p[2], h = p[3], cf = p[4];
    float hw_ = w * 0.5f, hh_ = h * 0.5f;  // w/2 exact
    float x1 = cx - hw_, y1 = cy - hh_, x2 = cx + hw_, y2 = cy + hh_;
    gx1[t] = x1; gy1[t] = y1; gx2[t] = x2; gy2[t] = y2;
    gar[t] = ((x2 - x1) + 1.0f) * ((y2 - y1) + 1.0f);
    float best = p[5]; int bc = 0;
#pragma unroll
    for (int c = 1; c < 20; ++c) {       // first-max argmax (numpy semantics)
        float v = p[5 + c];
        if (v > best) { best = v; bc = c; }
    }
    bool valid = (cf >= 0.5f);
    gcv[t] = (uint32)bc | (valid ? 0x100u : 0u);
    unsigned long long bal = __ballot(valid);   // t is wave-aligned
    if ((t & 63) == 0) {
        vwords[(t >> 5) + 0] = (uint32)bal;
        vwords[(t >> 5) + 1] = (uint32)(bal >> 32);
    }
}

// ---------------- NMS stage 2: suppression bitmask build ----------------
// Strict-upper-triangle only (bits j<=i left as poison: provably never
// consumed by scan). Block = pair of 64-row strips (p, 31-p) -> constant
// 33 col-group rounds/block. grid (16, B) = 256 blocks = 1/CU.
// Lane = column within 64-col group; full 64-bit row words via __ballot.
// Exact div-free threshold: round(inter/denom) >= 0.4f  <=>
//   (double)inter > KMID*(double)denom,  KMID = (pred(0.4f)+0.4f)/2
//   (tie rounds to even = pred < 0.4f, so strict >). Product of 25-bit
//   KMID and 24-bit denom is exact in f64; denom > 0 always.
#define KMID (13421772.5 / 33554432.0)
__global__ __launch_bounds__(1024) void build_kernel(const float* __restrict__ gx1,
                                                     const float* __restrict__ gy1,
                                                     const float* __restrict__ gx2,
                                                     const float* __restrict__ gy2,
                                                     const float* __restrict__ gar,
                                                     const uint32* __restrict__ gcv,
                                                     uint32* __restrict__ rowmask) {
    __shared__ float4 x4s[TOPK];    // 32 KiB (plain layout)
    __shared__ float  ars[TOPK];    // 8 KiB
    __shared__ uint32 clss[TOPK];   // 8 KiB
    int bt   = blockIdx.y;
    int pr   = blockIdx.x;          // pair 0..15
    int tid  = threadIdx.x;
    int lane = tid & 63;
    int wvq  = tid >> 6;            // row-quad 0..15
    int base = bt * TOPK;
    u64* rm64 = (u64*)(rowmask + (size_t)base * NWORD);   // [row][32] u64

    for (int j = tid; j < TOPK; j += 1024) {
        int g = base + j;
        x4s[j]  = make_float4(gx1[g], gy1[g], gx2[g], gy2[g]);
        ars[j]  = gar[g];
        clss[j] = gcv[g] & 0xffu;
    }
    __syncthreads();

#pragma unroll
    for (int s = 0; s < 2; ++s) {
        int r = s ? (31 - pr) : pr;         // strip index
        int i0 = r * 64 + wvq * 4;          // this wave's 4 rows
        float4 rq[4]; float rar4[4]; uint32 rcl4[4];
#pragma unroll
        for (int k = 0; k < 4; ++k) {
            rq[k] = x4s[i0 + k]; rar4[k] = ars[i0 + k]; rcl4[k] = clss[i0 + k];
        }
        for (int cg = r; cg < 32; ++cg) {
            int j = cg * 64 + lane;
            float4 c  = x4s[j];
            float car = ars[j];
            uint32 cc = clss[j];
            u64 bal[4];
#pragma unroll
            for (int k = 0; k < 4; ++k) {
                float ix1 = fmaxf(rq[k].x, c.x);
                float iy1 = fmaxf(rq[k].y, c.y);
                float ix2 = fminf(rq[k].z, c.z);
                float iy2 = fminf(rq[k].w, c.w);
                float iw = fmaxf((ix2 - ix1) + 1.0f, 0.0f);
                float ih = fmaxf((iy2 - iy1) + 1.0f, 0.0f);
                float inter = iw * ih;
                float denom = ((rar4[k] + car) - inter) + 1e-16f;
                bool cond = ((double)inter > KMID * (double)denom) && (cc == rcl4[k]);
                bal[k] = __ballot(cond);
            }
            u64 v = bal[0];
            if (lane == 1) v = bal[1];
            if (lane == 2) v = bal[2];
            if (lane == 3) v = bal[3];
            if (lane < 4) rm64[(size_t)(i0 + lane) * 32 + cg] = v;
        }
    }
}

// ---------------- NMS stage 3: serial greedy scan via LDS streaming -------
// 1 block/batch, 1024 thr: wave 0 scans chunk c from LDS while waves 1-15
// copy chunk c+1 (32 KB) global->LDS double buffer.
#define SPF 8
__global__ __launch_bounds__(1024) void scan_kernel(const uint32* __restrict__ rowmask,
                                                    const uint32* __restrict__ vwords,
                                                    float* __restrict__ keepf) {
    __shared__ uint32 buf[2][CH * NWORD];   // 2 x 32 KiB
    int bt  = blockIdx.x;
    int tid = threadIdx.x;
    int wv  = tid >> 6;
    int l   = tid & 63;
    const uint32* rm = rowmask + (size_t)bt * TOPK * NWORD;

    if (wv > 0) {
        int ctid = tid - 64;
        const uint4* src = (const uint4*)rm;
        uint4* dst = (uint4*)buf[0];
        for (int o = ctid; o < CH * NWORD / 4; o += 960) dst[o] = src[o];
    }
    uint32 vw = 0, supp = 0, keepw = 0, cur = 0, vcur = 0;
    if (wv == 0) vw = vwords[bt * 64 + l];
    __syncthreads();

    for (int c = 0; c < NCHUNK; ++c) {
        if (wv > 0) {
            if (c + 1 < NCHUNK) {
                int ctid = tid - 64;
                const uint4* src = (const uint4*)(rm + (size_t)(c + 1) * CH * NWORD);
                uint4* dst = (uint4*)buf[(c + 1) & 1];
                for (int o = ctid; o < CH * NWORD / 4; o += 960) dst[o] = src[o];
            }
        } else {
            const uint32* bp = buf[c & 1];
            uint32 rlb[SPF], rwb[SPF];
#pragma unroll
            for (int k = 0; k < SPF; ++k) {
                rlb[k] = bp[k * NWORD + l];
                rwb[k] = bp[k * NWORD + ((c * CH + k) >> 5)];
            }
            for (int kk = 0; kk < CH; kk += SPF) {
#pragma unroll
                for (int k2 = 0; k2 < SPF; ++k2) {
                    int k = kk + k2;
                    int i = c * CH + k;
                    uint32 rl = rlb[k2], rw = rwb[k2];
                    int nk = k + SPF;
                    if (nk < CH) {
                        rlb[k2] = bp[nk * NWORD + l];
                        rwb[k2] = bp[nk * NWORD + ((c * CH + nk) >> 5)];
                    }
                    int b2 = i & 31;
                    if (b2 == 0) {
                        cur  = __shfl(supp, i >> 5);
                        vcur = __shfl(vw,   i >> 5);
                    }
                    uint32 kf = ((vcur >> b2) & ~(cur >> b2)) & 1u;
                    uint32 m = (uint32)(-(int)kf);
                    cur  |= rw & m;
                    supp |= rl & m;
                    if (l == (i >> 5)) keepw |= kf << b2;
                }
            }
        }
        __syncthreads();
    }

    if (wv == 0) {
#pragma unroll
        for (int k = 0; k < 32; ++k)
            keepf[bt * TOPK + l * 32 + k] = (float)((keepw >> k) & 1u);
    }
}

extern "C" void kernel_launch(void* const* d_in, const int* in_sizes, int n_in,
                              void* d_out, int out_size, void* d_ws, size_t ws_size,
                              hipStream_t stream) {
    const float* inp     = (const float*)d_in[0];
    const float* anchors = (const float*)d_in[1];
    float* out   = (float*)d_out;                        // [B, N, 25]
    float* topf  = out  + (size_t)B * NCAND * CATTR;     // [B, 2048] indices as float
    float* keepf = topf + (size_t)B * TOPK;              // [B, 2048] 0/1 as float

    // workspace layout
    float*  cws = (float*)d_ws;                          // [B, NCAND] conf
    float*  gx1 = cws + B * NCAND;
    float*  gy1 = gx1 + B * TOPK;
    float*  gx2 = gy1 + B * TOPK;
    float*  gy2 = gx2 + B * TOPK;
    float*  gar = gy2 + B * TOPK;
    uint32* gcv = (uint32*)(gar + B * TOPK);
    uint32* rowmask = gcv + B * TOPK;                    // 16*2048*64 u32 = 8 MiB
    uint32* vwords  = rowmask + (size_t)B * TOPK * NWORD;
    // sort scratch aliases onto rowmask (sort completes before build writes)
    u64* runs = (u64*)rowmask;                           // 1 MiB
    u64* half = runs + (size_t)B * 4 * 2048;             // 0.5 MiB

    int total = B * NCAND;
    decode_kernel<<<(total + 255) / 256, 256, 0, stream>>>(inp, anchors, out, cws);
    sort1_kernel<<<B * 4, 256, 0, stream>>>(cws, runs);
    sort2_kernel<<<B * 2, 256, 0, stream>>>(runs, half);
    sort3_kernel<<<B, 256, 0, stream>>>(half, topf);
    geo_kernel<<<(B * TOPK + 255) / 256, 256, 0, stream>>>(out, topf, gx1, gy1, gx2, gy2, gar, gcv, vwords);
    build_kernel<<<dim3(16, B), 1024, 0, stream>>>(gx1, gy1, gx2, gy2, gar, gcv, rowmask);
    scan_kernel<<<B, 1024, 0, stream>>>(rowmask, vwords, keepf);
}